// Round 16
// baseline (282.557 us; speedup 1.0000x reference)
//
#include <hip/hip_runtime.h>

typedef __attribute__((ext_vector_type(8))) __bf16 bf16x8;
typedef __attribute__((ext_vector_type(4))) float f32x4;

__device__ __forceinline__ bf16x8 cvt8(f32x4 a, f32x4 b) {
    bf16x8 v;
    v[0] = (__bf16)a.x; v[1] = (__bf16)a.y; v[2] = (__bf16)a.z; v[3] = (__bf16)a.w;
    v[4] = (__bf16)b.x; v[5] = (__bf16)b.y; v[6] = (__bf16)b.z; v[7] = (__bf16)b.w;
    return v;
}

// VALU-pipe cross-lane add via DPP
template <int CTRL>
__device__ __forceinline__ float dpp_addf(float v) {
    union { float f; int i; } s, r;
    s.f = v;
    r.i = __builtin_amdgcn_update_dpp(0, s.i, CTRL, 0xF, 0xF, true);
    return v + r.f;
}

// ---------------------------------------------------------------------------
// Kernel 0: zero the sums+counts workspace (fast, known-cost).
// ---------------------------------------------------------------------------
__global__ void zero_ws(float* __restrict__ p, int n4)
{
    const int i = blockIdx.x * blockDim.x + threadIdx.x;
    if (i < n4) *(f32x4*)(p + 4 * i) = (f32x4)0.f;
}

// ---------------------------------------------------------------------------
// Kernel 1: BARRIER-FREE row-split. W (lin|gate) staged once to 64KB LDS
// (bf16, XOR-swizzled), one __syncthreads, then each wave free-runs a
// contiguous 256-row range: 16 rows/step, ALL 256 output cols per wave.
// x: global->register->A-frag (no x staging). Softmax fully wave-local
// (in-lane over col-tiles + DPP 16-lane reduce). Per-graph col sums in
// registers; atomics + counts only at graph boundaries.
// ---------------------------------------------------------------------------
__global__ __launch_bounds__(256, 2) void gnn_main(
    const float* __restrict__ x, const int* __restrict__ batch,
    const float* __restrict__ Wlin, const float* __restrict__ blin,
    const float* __restrict__ Wgate, const float* __restrict__ bgate,
    float* __restrict__ sums, float* __restrict__ counts, int nN, int PW)
{
    __shared__ __bf16 WS[2][128 * 128];   // [0]=lin, [1]=gate; 32 KB each

    const int tid  = threadIdx.x;
    const int lane = tid & 63;
    const int w    = tid >> 6;    // wave 0..3
    const int l15  = lane & 15;
    const int lg   = lane >> 4;   // 0..3

    // ---- one-time W stage (bf16, swizzle byte ^= (row&7)<<4)
    for (int idx = tid; idx < 4096; idx += 256) {
        const int c   = idx >> 4;      // 0..255
        const int kg  = idx & 15;
        const int row = c & 127;
        const float* src = (c < 128 ? Wlin : Wgate) + (size_t)row * 128 + kg * 8;
        f32x4 u0 = *(const f32x4*)src;
        f32x4 u1 = *(const f32x4*)(src + 4);
        const int byte = (row * 256 + kg * 16) ^ ((row & 7) << 4);
        *(bf16x8*)((char*)&WS[c >> 7][0] + byte) = cvt8(u0, u1);
    }
    float bl[8], bg[8];
#pragma unroll
    for (int j = 0; j < 8; ++j) {
        bl[j] = blin[j * 16 + l15];
        bg[j] = bgate[j * 16 + l15];
    }
    __syncthreads();   // the ONLY barrier

    // ---- this wave's contiguous range
    const int wid = blockIdx.x * 4 + w;
    const long r0l = (long)wid * PW;
    if (r0l >= nN) return;
    const int R0 = (int)r0l;
    const int R1 = min(R0 + PW, nN);
    const int nt = (R1 - R0 + 15) >> 4;

    float racc[8];
#pragma unroll
    for (int j = 0; j < 8; ++j) racc[j] = 0.f;
    int ncnt = 0;
    int gcur = batch[R0];

    auto flush = [&](int g) {
#pragma unroll
        for (int j = 0; j < 8; ++j) {
            float v = racc[j];
            v += __shfl_xor(v, 16);
            v += __shfl_xor(v, 32);
            if (lg == 0) atomicAdd(sums + (size_t)g * 128 + j * 16 + l15, v);
            racc[j] = 0.f;
        }
        if (lane == 0) atomicAdd(counts + g, (float)ncnt);
        ncnt = 0;
    };

    // ---- x prefetch: lane covers row l15, k-slice [lg*8 + kk*32, +8)
    f32x4 pf[8];
    int   btn;
    auto issue = [&](int base) {
        const int nd = base + l15;
        const float* p = x + (size_t)(nd < nN ? nd : nN - 1) * 128 + lg * 8;
#pragma unroll
        for (int k = 0; k < 4; ++k) {
            pf[2 * k]     = *(const f32x4*)(p + k * 32);
            pf[2 * k + 1] = *(const f32x4*)(p + k * 32 + 4);
        }
        btn = (nd < nN) ? batch[nd] : -1;
    };

    issue(R0);
    int bt = btn;

    for (int t = 0; t < nt; ++t) {
        const int base = R0 + (t << 4);

        // ---- convert current tile to A-frags (counted vmcnt waits here)
        bf16x8 afr[4];
#pragma unroll
        for (int k = 0; k < 4; ++k) afr[k] = cvt8(pf[2 * k], pf[2 * k + 1]);
        if (t + 1 < nt) issue(base + 16);   // next tile in flight through GEMMs

        // ---- gate pass: 32 MFMA over 8 col-tiles
        f32x4 aG[8];
#pragma unroll
        for (int j = 0; j < 8; ++j) aG[j] = (f32x4)0.f;
#pragma unroll
        for (int kk = 0; kk < 4; ++kk) {
#pragma unroll
            for (int j = 0; j < 8; ++j) {
                const int c    = j * 16 + l15;
                const int byte = (c * 256 + kk * 64 + lg * 16) ^ ((c & 7) << 4);
                bf16x8 bfr = *(const bf16x8*)((const char*)&WS[1][0] + byte);
                aG[j] = __builtin_amdgcn_mfma_f32_16x16x32_bf16(afr[kk], bfr, aG[j], 0, 0, 0);
            }
        }

        // ---- softmax: in-lane col-tile sum + DPP 16-lane row reduce
        f32x4 rs = (f32x4)0.f;
#pragma unroll
        for (int j = 0; j < 8; ++j) {
#pragma unroll
            for (int r = 0; r < 4; ++r) {
                float e = __expf(aG[j][r] + bg[j]);
                aG[j][r] = e;
                rs[r] += e;
            }
        }
        f32x4 inv;
#pragma unroll
        for (int r = 0; r < 4; ++r) {
            float s = rs[r];
            s = dpp_addf<0x128>(s);   // row_ror:8
            s = dpp_addf<0x124>(s);   // row_ror:4
            s = dpp_addf<0x122>(s);   // row_ror:2
            s = dpp_addf<0x121>(s);   // row_ror:1
            inv[r] = 1.0f / s;
        }

        // ---- state pass: 32 MFMA
        f32x4 aS[8];
#pragma unroll
        for (int j = 0; j < 8; ++j) aS[j] = (f32x4)0.f;
#pragma unroll
        for (int kk = 0; kk < 4; ++kk) {
#pragma unroll
            for (int j = 0; j < 8; ++j) {
                const int c    = j * 16 + l15;
                const int byte = (c * 256 + kk * 64 + lg * 16) ^ ((c & 7) << 4);
                bf16x8 bfr = *(const bf16x8*)((const char*)&WS[0][0] + byte);
                aS[j] = __builtin_amdgcn_mfma_f32_16x16x32_bf16(afr[kk], bfr, aS[j], 0, 0, 0);
            }
        }

        // ---- gating (fully in-lane; rows = lg*4 + r)
#pragma unroll
        for (int j = 0; j < 8; ++j)
#pragma unroll
            for (int r = 0; r < 4; ++r)
                aS[j][r] = (aS[j][r] + bl[j]) * aG[j][r] * inv[r];

        // ---- segmented accumulation over this wave's 16 sorted rows
        const int nvalid = min(16, R1 - base);
        const int gf = __builtin_amdgcn_readlane(bt, 0);
        const int gl = __builtin_amdgcn_readlane(bt, nvalid - 1);
        if (nvalid == 16 && gf == gl) {
            if (gf != gcur) { flush(gcur); gcur = gf; }
#pragma unroll
            for (int j = 0; j < 8; ++j)
                racc[j] += (aS[j][0] + aS[j][1]) + (aS[j][2] + aS[j][3]);
            ncnt += 16;
        } else {
            int rid[4];
#pragma unroll
            for (int r = 0; r < 4; ++r) {
                const int rr = lg * 4 + r;
                rid[r] = (rr < nvalid) ? __shfl(bt, rr) : -1;
            }
            const unsigned long long vm = ((1ull << nvalid) - 1ull) & 0xFFFFull;
            for (int g = gf; g <= gl; ++g) {
                if (g != gcur) { flush(gcur); gcur = g; }
                const int cg = __popcll(__ballot(bt == g) & vm);
#pragma unroll
                for (int j = 0; j < 8; ++j) {
                    float cs = 0.f;
#pragma unroll
                    for (int r = 0; r < 4; ++r)
                        cs += (rid[r] == g) ? aS[j][r] : 0.f;
                    racc[j] += cs;
                }
                ncnt += cg;
            }
        }
        bt = btn;
    }
    flush(gcur);
}

// ---------------------------------------------------------------------------
// Kernel 2: 8 graphs per block. mean = sums/clip(counts,1);
// out = mean @ Wf^T + bf
// ---------------------------------------------------------------------------
__global__ __launch_bounds__(128) void final_mm(
    const float* __restrict__ sums, const float* __restrict__ counts,
    const float* __restrict__ Wf, const float* __restrict__ bf,
    float* __restrict__ out)
{
    const int c  = threadIdx.x;          // col 0..127
    const int g0 = blockIdx.x * 8;
    __shared__ float m[8][128];
#pragma unroll
    for (int j = 0; j < 8; ++j) {
        const float invC = 1.0f / fmaxf(counts[g0 + j], 1.0f);
        m[j][c] = sums[(size_t)(g0 + j) * 128 + c] * invC;
    }
    __syncthreads();
    float acc[8];
    const float b = bf[c];
#pragma unroll
    for (int j = 0; j < 8; ++j) acc[j] = b;
    const f32x4* wr = (const f32x4*)(Wf + (size_t)c * 128);
#pragma unroll
    for (int k = 0; k < 32; ++k) {
        f32x4 wv = wr[k];
#pragma unroll
        for (int j = 0; j < 8; ++j) {
            f32x4 mv = *(const f32x4*)&m[j][4 * k];
            acc[j] += mv.x * wv.x + mv.y * wv.y + mv.z * wv.z + mv.w * wv.w;
        }
    }
#pragma unroll
    for (int j = 0; j < 8; ++j) out[(size_t)(g0 + j) * 128 + c] = acc[j];
}

extern "C" void kernel_launch(void* const* d_in, const int* in_sizes, int n_in,
                              void* d_out, int out_size, void* d_ws, size_t ws_size,
                              hipStream_t stream)
{
    const float* x     = (const float*)d_in[0];
    const int*   batch = (const int*)d_in[1];
    const float* Wlin  = (const float*)d_in[2];
    const float* blin  = (const float*)d_in[3];
    const float* Wgate = (const float*)d_in[4];
    const float* bgate = (const float*)d_in[5];
    const float* Wfin  = (const float*)d_in[6];
    const float* bfin  = (const float*)d_in[7];
    float* out    = (float*)d_out;
    float* sums   = (float*)d_ws;                             // 512 KB
    float* counts = (float*)((char*)d_ws + 512 * 1024);       // 4 KB

    const int nNodes  = in_sizes[1];
    const int nGraphs = out_size / 128;

    // 256 rows per wave, 4 waves per block -> ~489 blocks (2 resident/CU)
    const int PW = 256;
    const int nWaves = (nNodes + PW - 1) / PW;
    const int nB = (nWaves + 3) / 4;

    const int nZ4 = (1024 * 128 + 1024) / 4;   // f32x4 chunks
    zero_ws<<<(nZ4 + 255) / 256, 256, 0, stream>>>(sums, nZ4);
    gnn_main<<<nB, 256, 0, stream>>>(x, batch, Wlin, blin, Wgate, bgate,
                                     sums, counts, nNodes, PW);
    final_mm<<<(nGraphs + 7) / 8, 128, 0, stream>>>(sums, counts, Wfin, bfin, out);
}

// Round 17
// 139.856 us; speedup vs baseline: 2.0203x; 2.0203x over previous
//
#include <hip/hip_runtime.h>

typedef __attribute__((ext_vector_type(8))) __bf16 bf16x8;
typedef __attribute__((ext_vector_type(4))) float f32x4;

__device__ __forceinline__ bf16x8 cvt8(f32x4 a, f32x4 b) {
    bf16x8 v;
    v[0] = (__bf16)a.x; v[1] = (__bf16)a.y; v[2] = (__bf16)a.z; v[3] = (__bf16)a.w;
    v[4] = (__bf16)b.x; v[5] = (__bf16)b.y; v[6] = (__bf16)b.z; v[7] = (__bf16)b.w;
    return v;
}

// VALU-pipe cross-lane add via DPP (replaces ds_swizzle-based __shfl_xor)
template <int CTRL>
__device__ __forceinline__ float dpp_addf(float v) {
    union { float f; int i; } s, r;
    s.f = v;
    r.i = __builtin_amdgcn_update_dpp(0, s.i, CTRL, 0xF, 0xF, true);
    return v + r.f;
}

// ---------------------------------------------------------------------------
// Kernel 0: zero 512KB accumulator + build graph offsets from sorted batch.
// ---------------------------------------------------------------------------
__global__ void prep(const int* __restrict__ batch, int nN,
                     float* __restrict__ sums, int* __restrict__ off)
{
    const int i = blockIdx.x * blockDim.x + threadIdx.x;
    const int stride = gridDim.x * blockDim.x;
    for (int t = i; t < 1024 * 128; t += stride) sums[t] = 0.f;
    for (int t = i; t < nN; t += stride) {
        const int b  = batch[t];
        const int bp = (t == 0) ? -1 : batch[t - 1];
        for (int g = bp + 1; g <= b; ++g) off[g] = t;
        if (t == nN - 1) {
            for (int g = b + 1; g <= 1024; ++g) off[g] = nN;
        }
    }
}

// ---------------------------------------------------------------------------
// Kernel 1: R10/R13 structure and bit-exact arithmetic (512 thr / 8 waves,
// 32-row bf16 tiles, 2x8KB XOR-swizzled x-buf, DPP softmax, lgkm-only
// barriers). ONE change vs R13: Wgate fragments move from 32 VGPRs to
// block-shared LDS (32KB, staged once) and launch_bounds(512,6) caps VGPR
// at ~85 so THREE blocks fit per CU (24 waves = 1.5x TLP for the
// latency-bound regime). Wlin fragments stay in registers.
// ---------------------------------------------------------------------------
__global__ __launch_bounds__(512, 6) void gnn_main(
    const float* __restrict__ x, const int* __restrict__ batch,
    const float* __restrict__ Wlin, const float* __restrict__ blin,
    const float* __restrict__ Wgate, const float* __restrict__ bgate,
    float* __restrict__ sums, int nN, int P)
{
    __shared__ __bf16 buf[2][32 * 128];   // 2 x 8 KB bf16, 16B-XOR swizzled
    __shared__ __bf16 WG[128 * 128];      // 32 KB: Wgate, XOR-swizzled
    __shared__ float  PS[8][36];          // per-wave row partial sums (padded)
    __shared__ float  invLds[32];         // per-row 1/sum

    const int tid  = threadIdx.x;
    const int lane = tid & 63;
    const int w    = tid >> 6;    // wave 0..7
    const int l15  = lane & 15;
    const int lg   = lane >> 4;   // 0..3

    const int R0 = blockIdx.x * P;
    if (R0 >= nN) return;
    const int R1b = min(R0 + P, nN);
    const int nt  = (R1b - R0 + 31) >> 5;

    // ---- one-time Wgate stage -> LDS (bf16, swizzle byte ^= (c&7)<<4)
    for (int idx = tid; idx < 2048; idx += 512) {
        const int c  = idx >> 4;      // col 0..127
        const int kg = idx & 15;      // 8-elem k group
        const float* src = Wgate + (size_t)c * 128 + kg * 8;
        f32x4 u0 = *(const f32x4*)src;
        f32x4 u1 = *(const f32x4*)(src + 4);
        const int byte = (c * 256 + kg * 16) ^ ((c & 7) << 4);
        *(bf16x8*)((char*)WG + byte) = cvt8(u0, u1);
    }

    // ---- Wlin fragments (B operand) in registers: rows [16w,16w+16)
    bf16x8 bfrag[4];
    {
        const float* Wp0 = Wlin + (size_t)(w * 16 + l15) * 128 + lg * 8;
#pragma unroll
        for (int kk = 0; kk < 4; ++kk)
            bfrag[kk] = cvt8(*(const f32x4*)(Wp0 + kk * 32),
                             *(const f32x4*)(Wp0 + kk * 32 + 4));
    }
    const float bl = blin[w * 16 + l15];
    const float bg = bgate[w * 16 + l15];

    // ---- staging: thread covers x[base + (tid>>4)][(tid&15)*8 .. +7]
    const int srow = tid >> 4;         // 0..31
    const int skg  = tid & 15;         // 8-elem group
    f32x4 lv0, lv1;
    int   btn;
    auto stage_load = [&](int base) {
        const int nd = base + srow;
        const float* p = x + (size_t)(nd < nN ? nd : nN - 1) * 128 + skg * 8;
        lv0 = *(const f32x4*)p;
        lv1 = *(const f32x4*)(p + 4);
        const int bi = base + lane;
        btn = (bi < nN) ? batch[bi] : -1;
    };
    auto stage_write = [&](int bsel) {   // counted vmcnt lands here
        const int byte = (srow * 256 + skg * 16) ^ ((srow & 7) << 4);
        *(bf16x8*)((char*)&buf[bsel][0] + byte) = cvt8(lv0, lv1);
    };

    float racc = 0.f;
    int   gcur = batch[R0];
    auto flush = [&](int g) {
        float v = racc;
        v += __shfl_xor(v, 16);
        v += __shfl_xor(v, 32);
        if (lg == 0) atomicAdd(sums + (size_t)g * 128 + w * 16 + l15, v);
        racc = 0.f;
    };

    // ---- prologue: tile 0 staged; tile 1 loads already in flight.
    // The lgkmcnt(0) below also covers the WG staging ds_writes.
    stage_load(R0);
    int bq0 = btn;                 // batch ids of tile t
    stage_write(0);
    if (nt > 1) stage_load(R0 + 32);
    int bq1 = btn;                 // batch ids of tile t+1
    asm volatile("s_waitcnt lgkmcnt(0)\n\ts_barrier" ::: "memory");

    for (int t = 0; t < nt; ++t) {
        const int base = R0 + (t << 5);

        // ---- fused dual GEMM from bf16 LDS tile; Wgate frags from LDS
        f32x4 accS[2], accG[2];
#pragma unroll
        for (int r16 = 0; r16 < 2; ++r16) { accS[r16] = (f32x4)0.f; accG[r16] = (f32x4)0.f; }
        const char* bc = (const char*)&buf[t & 1][0];
        const int   cg16 = w * 16 + l15;   // this lane's gate col
#pragma unroll
        for (int kk = 0; kk < 4; ++kk) {
            const int gbyte = (cg16 * 256 + kk * 64 + lg * 16) ^ ((cg16 & 7) << 4);
            bf16x8 gfr = *(const bf16x8*)((const char*)WG + gbyte);
#pragma unroll
            for (int r16 = 0; r16 < 2; ++r16) {
                const int row  = r16 * 16 + l15;
                const int byte = (row * 256 + kk * 64 + lg * 16) ^ ((l15 & 7) << 4);
                bf16x8 af = *(const bf16x8*)(bc + byte);
                accS[r16] = __builtin_amdgcn_mfma_f32_16x16x32_bf16(af, bfrag[kk], accS[r16], 0, 0, 0);
                accG[r16] = __builtin_amdgcn_mfma_f32_16x16x32_bf16(af, gfr, accG[r16], 0, 0, 0);
            }
        }

        // ---- exp + 16-lane row sums on the VALU (DPP ror 8/4/2/1)
#pragma unroll
        for (int r16 = 0; r16 < 2; ++r16) {
            f32x4 pv;
#pragma unroll
            for (int r = 0; r < 4; ++r) {
                float e = __expf(accG[r16][r] + bg);
                accG[r16][r] = e;
                float s = e;
                s = dpp_addf<0x128>(s);   // row_ror:8
                s = dpp_addf<0x124>(s);   // row_ror:4
                s = dpp_addf<0x122>(s);   // row_ror:2
                s = dpp_addf<0x121>(s);   // row_ror:1
                pv[r] = s;
            }
            if (l15 == 0) *(f32x4*)&PS[w][r16 * 16 + lg * 4] = pv;
        }

        if (t + 1 < nt) stage_write((t + 1) & 1);   // consume lv (counted vmcnt)
        if (t + 2 < nt) stage_load(base + 64);      // re-issue, full iter ahead
        asm volatile("s_waitcnt lgkmcnt(0)\n\ts_barrier" ::: "memory");  // B1

        // ---- stage 2: rows [4w,4w+4), 8 partials each (x2 duplicated)
        {
            const int rw = w * 4 + (lane >> 4);
            float v = PS[lane & 7][rw];
            v = dpp_addf<0x124>(v);   // ror:4 == xor:4 under 8-dup
            v = dpp_addf<0x4E>(v);    // quad_perm(2,3,0,1) == xor:2
            v = dpp_addf<0xB1>(v);    // quad_perm(1,0,3,2) == xor:1
            if ((lane & 15) == 0) invLds[rw] = 1.0f / v;
        }
        asm volatile("s_waitcnt lgkmcnt(0)\n\ts_barrier" ::: "memory");  // B2

        // ---- gating
#pragma unroll
        for (int r16 = 0; r16 < 2; ++r16) {
            f32x4 iv = *(const f32x4*)&invLds[r16 * 16 + lg * 4];
#pragma unroll
            for (int r = 0; r < 4; ++r)
                accS[r16][r] = (accS[r16][r] + bl) * accG[r16][r] * iv[r];
        }

        // ---- segmented per-graph accumulation (rows base..base+31, sorted)
        const int bt = bq0;
        const int nvalid = min(32, nN - base);
        const int gf = __builtin_amdgcn_readlane(bt, 0);
        const int gl = __builtin_amdgcn_readlane(bt, nvalid - 1);
        if (nvalid == 32 && gf == gl) {
            if (gf != gcur) { flush(gcur); gcur = gf; }
            float ts = 0.f;
#pragma unroll
            for (int r16 = 0; r16 < 2; ++r16)
#pragma unroll
                for (int r = 0; r < 4; ++r) ts += accS[r16][r];
            racc += ts;
        } else {
            for (int g = gf; g <= gl; ++g) {
                float cs = 0.f;
#pragma unroll
                for (int r16 = 0; r16 < 2; ++r16)
#pragma unroll
                    for (int r = 0; r < 4; ++r) {
                        const int bid = __shfl(bt, r16 * 16 + lg * 4 + r);
                        cs += (bid == g) ? accS[r16][r] : 0.f;
                    }
                if (g == gcur) racc += cs;
                else { flush(gcur); gcur = g; racc = cs; }
            }
        }
        bq0 = bq1;
        bq1 = btn;
    }
    flush(gcur);
}

// ---------------------------------------------------------------------------
// Kernel 2: mean = sums/count, out = mean @ Wf^T + bf
// ---------------------------------------------------------------------------
__global__ __launch_bounds__(128) void final_mm(
    const float* __restrict__ sums, const int* __restrict__ off,
    const float* __restrict__ Wf, const float* __restrict__ bf,
    float* __restrict__ out)
{
    const int g = blockIdx.x, c = threadIdx.x;
    __shared__ float m[128];
    const int cnt = off[g + 1] - off[g];
    const float invC = 1.0f / (float)(cnt > 0 ? cnt : 1);
    m[c] = sums[g * 128 + c] * invC;
    __syncthreads();
    float acc = bf[c];
    const f32x4* wr = (const f32x4*)(Wf + (size_t)c * 128);
#pragma unroll
    for (int k = 0; k < 32; ++k) {
        f32x4 wv = wr[k];
        acc += m[4 * k] * wv.x + m[4 * k + 1] * wv.y + m[4 * k + 2] * wv.z + m[4 * k + 3] * wv.w;
    }
    out[g * 128 + c] = acc;
}

extern "C" void kernel_launch(void* const* d_in, const int* in_sizes, int n_in,
                              void* d_out, int out_size, void* d_ws, size_t ws_size,
                              hipStream_t stream)
{
    const float* x     = (const float*)d_in[0];
    const int*   batch = (const int*)d_in[1];
    const float* Wlin  = (const float*)d_in[2];
    const float* blin  = (const float*)d_in[3];
    const float* Wgate = (const float*)d_in[4];
    const float* bgate = (const float*)d_in[5];
    const float* Wfin  = (const float*)d_in[6];
    const float* bfin  = (const float*)d_in[7];
    float* out  = (float*)d_out;
    float* sums = (float*)d_ws;                               // 512 KB
    int*   off  = (int*)((char*)d_ws + 512 * 1024);           // 1025 ints

    const int nNodes  = in_sizes[1];
    const int nGraphs = out_size / 128;

    // ~977 blocks, contiguous ranges, P multiple of 32
    const int P  = ((((nNodes + 1023) / 1024) + 31) & ~31);
    const int nB = (nNodes + P - 1) / P;

    prep<<<1024, 256, 0, stream>>>(batch, nNodes, sums, off);
    gnn_main<<<nB, 512, 0, stream>>>(x, batch, Wlin, blin, Wgate, bgate, sums, nNodes, P);
    final_mm<<<nGraphs, 128, 0, stream>>>(sums, off, Wfin, bfin, out);
}

// Round 18
// 91.940 us; speedup vs baseline: 3.0733x; 1.5212x over previous
//
#include <hip/hip_runtime.h>

typedef __attribute__((ext_vector_type(8))) __bf16 bf16x8;
typedef __attribute__((ext_vector_type(4))) float f32x4;

__device__ __forceinline__ bf16x8 cvt8(f32x4 a, f32x4 b) {
    bf16x8 v;
    v[0] = (__bf16)a.x; v[1] = (__bf16)a.y; v[2] = (__bf16)a.z; v[3] = (__bf16)a.w;
    v[4] = (__bf16)b.x; v[5] = (__bf16)b.y; v[6] = (__bf16)b.z; v[7] = (__bf16)b.w;
    return v;
}

// VALU-pipe cross-lane add via DPP
template <int CTRL>
__device__ __forceinline__ float dpp_addf(float v) {
    union { float f; int i; } s, r;
    s.f = v;
    r.i = __builtin_amdgcn_update_dpp(0, s.i, CTRL, 0xF, 0xF, true);
    return v + r.f;
}

// ---------------------------------------------------------------------------
// Kernel 0: zero 512KB accumulator + build graph offsets from sorted batch.
// ---------------------------------------------------------------------------
__global__ void prep(const int* __restrict__ batch, int nN,
                     float* __restrict__ sums, int* __restrict__ off)
{
    const int i = blockIdx.x * blockDim.x + threadIdx.x;
    const int stride = gridDim.x * blockDim.x;
    for (int t = i; t < 1024 * 128; t += stride) sums[t] = 0.f;
    for (int t = i; t < nN; t += stride) {
        const int b  = batch[t];
        const int bp = (t == 0) ? -1 : batch[t - 1];
        for (int g = bp + 1; g <= b; ++g) off[g] = t;
        if (t == nN - 1) {
            for (int g = b + 1; g <= 1024; ++g) off[g] = nN;
        }
    }
}

// ---------------------------------------------------------------------------
// Kernel 1: SINGLE-BARRIER pipeline on the R10 base. Per iteration:
//   GEMM_t -> exp_t -> PS_t -> park {E_t(bf16), accS_t(f32)} in lane-private
//   LDS -> stage2_{t-1} (invLds) -> stage t+1/t+2 -> ONE barrier ->
//   unpark+gate+accumulate tile t-1.
// Rendezvous count halves vs R10 (the phase-locked 2-block convoy idles at
// every barrier; fewer barriers = less idle). Peak VGPR stays ~125 because
// only one acc set is live during the GEMM (previous tile is parked).
// ---------------------------------------------------------------------------
__global__ __launch_bounds__(512, 2) void gnn_main(
    const float* __restrict__ x, const int* __restrict__ batch,
    const float* __restrict__ Wlin, const float* __restrict__ blin,
    const float* __restrict__ Wgate, const float* __restrict__ bgate,
    float* __restrict__ sums, int nN, int P)
{
    __shared__ __bf16 buf[2][32 * 128];     // 16 KB x-tiles, 16B-XOR swizzled
    __shared__ float  parkS0[2][512 * 4];   // 16 KB accS[0] (lane-private)
    __shared__ float  parkS1[2][512 * 4];   // 16 KB accS[1]
    __shared__ __bf16 parkE[2][512 * 8];    // 16 KB exp values (bf16)
    __shared__ float  PS[2][8][36];         // row partial sums (dbuf)
    __shared__ float  invLds[2][32];        // per-row 1/sum (dbuf)

    const int tid  = threadIdx.x;
    const int lane = tid & 63;
    const int w    = tid >> 6;    // wave 0..7
    const int l15  = lane & 15;
    const int lg   = lane >> 4;   // 0..3

    const int R0 = blockIdx.x * P;
    if (R0 >= nN) return;
    const int R1b = min(R0 + P, nN);
    const int nt  = (R1b - R0 + 31) >> 5;

    // ---- W fragments (B operand): rows [16w,16w+16) of Wlin / Wgate
    bf16x8 bfrag[2][4];
    {
        const float* Wp0 = Wlin  + (size_t)(w * 16 + l15) * 128 + lg * 8;
        const float* Wp1 = Wgate + (size_t)(w * 16 + l15) * 128 + lg * 8;
#pragma unroll
        for (int kk = 0; kk < 4; ++kk) {
            bfrag[0][kk] = cvt8(*(const f32x4*)(Wp0 + kk * 32),
                                *(const f32x4*)(Wp0 + kk * 32 + 4));
            bfrag[1][kk] = cvt8(*(const f32x4*)(Wp1 + kk * 32),
                                *(const f32x4*)(Wp1 + kk * 32 + 4));
        }
    }
    const float bl = blin[w * 16 + l15];
    const float bg = bgate[w * 16 + l15];

    // ---- staging: thread covers x[base + (tid>>4)][(tid&15)*8 .. +7]
    const int srow = tid >> 4;
    const int skg  = tid & 15;
    f32x4 lv0, lv1;
    int   btn;
    auto stage_load = [&](int base) {
        const int nd = base + srow;
        const float* p = x + (size_t)(nd < nN ? nd : nN - 1) * 128 + skg * 8;
        lv0 = *(const f32x4*)p;
        lv1 = *(const f32x4*)(p + 4);
        const int bi = base + lane;
        btn = (bi < nN) ? batch[bi] : -1;
    };
    auto stage_write = [&](int bsel) {
        const int byte = (srow * 256 + skg * 16) ^ ((srow & 7) << 4);
        *(bf16x8*)((char*)&buf[bsel][0] + byte) = cvt8(lv0, lv1);
    };

    float racc = 0.f;
    int   gcur = batch[R0];
    auto flush = [&](int g) {
        float v = racc;
        v += __shfl_xor(v, 16);
        v += __shfl_xor(v, 32);
        if (lg == 0) atomicAdd(sums + (size_t)g * 128 + w * 16 + l15, v);
        racc = 0.f;
    };

    // gate + segmented accumulation of a parked tile (parity pb, ids bt)
    auto process = [&](int pt, int pb, int bt) {
        bf16x8 Ev = *(const bf16x8*)&parkE[pb][tid * 8];
        f32x4 s0 = *(const f32x4*)&parkS0[pb][tid * 4];
        f32x4 s1 = *(const f32x4*)&parkS1[pb][tid * 4];
        f32x4 iv0 = *(const f32x4*)&invLds[pb][lg * 4];
        f32x4 iv1 = *(const f32x4*)&invLds[pb][16 + lg * 4];
        f32x4 gs0, gs1;
#pragma unroll
        for (int r = 0; r < 4; ++r) {
            gs0[r] = (s0[r] + bl) * (float)Ev[r]     * iv0[r];
            gs1[r] = (s1[r] + bl) * (float)Ev[4 + r] * iv1[r];
        }
        const int base = R0 + (pt << 5);
        const int nvalid = min(32, nN - base);
        const int gf = __builtin_amdgcn_readlane(bt, 0);
        const int gl = __builtin_amdgcn_readlane(bt, nvalid - 1);
        if (nvalid == 32 && gf == gl) {
            if (gf != gcur) { flush(gcur); gcur = gf; }
            racc += (gs0[0] + gs0[1]) + (gs0[2] + gs0[3])
                  + (gs1[0] + gs1[1]) + (gs1[2] + gs1[3]);
        } else {
            for (int g = gf; g <= gl; ++g) {
                float cs = 0.f;
#pragma unroll
                for (int r = 0; r < 4; ++r) {
                    const int b0 = __shfl(bt, lg * 4 + r);
                    const int b1 = __shfl(bt, 16 + lg * 4 + r);
                    cs += (b0 == g) ? gs0[r] : 0.f;
                    cs += (b1 == g) ? gs1[r] : 0.f;
                }
                if (g == gcur) racc += cs;
                else { flush(gcur); gcur = g; racc = cs; }
            }
        }
    };

    // ---- prologue: tile 0 staged; tile 1 loads in flight
    stage_load(R0);
    int bq_cur = btn;
    stage_write(0);
    if (nt > 1) stage_load(R0 + 32);
    int bq_next = btn;
    int bq_prev = 0;
    asm volatile("s_waitcnt lgkmcnt(0)\n\ts_barrier" ::: "memory");

    for (int t = 0; t < nt; ++t) {
        const int cb = t & 1, pb = cb ^ 1;
        const int base = R0 + (t << 5);

        // ---- fused dual GEMM from bf16 LDS tile buf[cb]
        f32x4 accS[2], accG[2];
#pragma unroll
        for (int r16 = 0; r16 < 2; ++r16) { accS[r16] = (f32x4)0.f; accG[r16] = (f32x4)0.f; }
        const char* bc = (const char*)&buf[cb][0];
#pragma unroll
        for (int kk = 0; kk < 4; ++kk) {
#pragma unroll
            for (int r16 = 0; r16 < 2; ++r16) {
                const int row  = r16 * 16 + l15;
                const int byte = (row * 256 + kk * 64 + lg * 16) ^ ((l15 & 7) << 4);
                bf16x8 af = *(const bf16x8*)(bc + byte);
                accS[r16] = __builtin_amdgcn_mfma_f32_16x16x32_bf16(af, bfrag[0][kk], accS[r16], 0, 0, 0);
                accG[r16] = __builtin_amdgcn_mfma_f32_16x16x32_bf16(af, bfrag[1][kk], accG[r16], 0, 0, 0);
            }
        }

        // ---- exp + 16-lane row sums (DPP) -> PS[cb]
#pragma unroll
        for (int r16 = 0; r16 < 2; ++r16) {
            f32x4 pv;
#pragma unroll
            for (int r = 0; r < 4; ++r) {
                float e = __expf(accG[r16][r] + bg);
                accG[r16][r] = e;
                float s = e;
                s = dpp_addf<0x128>(s);   // row_ror:8
                s = dpp_addf<0x124>(s);   // row_ror:4
                s = dpp_addf<0x122>(s);   // row_ror:2
                s = dpp_addf<0x121>(s);   // row_ror:1
                pv[r] = s;
            }
            if (l15 == 0) *(f32x4*)&PS[cb][w][r16 * 16 + lg * 4] = pv;
        }

        // ---- park tile t (lane-private, conflict-free 16B stride)
        *(bf16x8*)&parkE[cb][tid * 8] = cvt8(accG[0], accG[1]);
        *(f32x4*)&parkS0[cb][tid * 4] = accS[0];
        *(f32x4*)&parkS1[cb][tid * 4] = accS[1];

        // ---- stage 2 for tile t-1: PS[pb] visible since previous barrier
        if (t > 0) {
            const int rw = w * 4 + (lane >> 4);
            float v = PS[pb][lane & 7][rw];
            v = dpp_addf<0x124>(v);   // ror:4 == xor:4 under 8-dup
            v = dpp_addf<0x4E>(v);    // quad_perm(2,3,0,1) == xor:2
            v = dpp_addf<0xB1>(v);    // quad_perm(1,0,3,2) == xor:1
            if ((lane & 15) == 0) invLds[pb][rw] = 1.0f / v;
        }

        if (t + 1 < nt) stage_write((t + 1) & 1);   // counted vmcnt on lv
        if (t + 2 < nt) stage_load(base + 64);

        // ---- the ONE barrier per tile
        asm volatile("s_waitcnt lgkmcnt(0)\n\ts_barrier" ::: "memory");

        // ---- gate + accumulate tile t-1 (invLds[pb] + park[pb] now usable)
        if (t > 0) process(t - 1, pb, bq_prev);

        bq_prev = bq_cur;
        bq_cur  = bq_next;
        bq_next = btn;
    }

    // ---- epilogue: finish tile nt-1
    {
        const int pb = (nt - 1) & 1;
        const int rw = w * 4 + (lane >> 4);
        float v = PS[pb][lane & 7][rw];
        v = dpp_addf<0x124>(v);
        v = dpp_addf<0x4E>(v);
        v = dpp_addf<0xB1>(v);
        if ((lane & 15) == 0) invLds[pb][rw] = 1.0f / v;
        asm volatile("s_waitcnt lgkmcnt(0)\n\ts_barrier" ::: "memory");
        process(nt - 1, pb, bq_prev);
    }
    flush(gcur);
}

// ---------------------------------------------------------------------------
// Kernel 2: mean = sums/count, out = mean @ Wf^T + bf
// ---------------------------------------------------------------------------
__global__ __launch_bounds__(128) void final_mm(
    const float* __restrict__ sums, const int* __restrict__ off,
    const float* __restrict__ Wf, const float* __restrict__ bf,
    float* __restrict__ out)
{
    const int g = blockIdx.x, c = threadIdx.x;
    __shared__ float m[128];
    const int cnt = off[g + 1] - off[g];
    const float invC = 1.0f / (float)(cnt > 0 ? cnt : 1);
    m[c] = sums[g * 128 + c] * invC;
    __syncthreads();
    float acc = bf[c];
    const f32x4* wr = (const f32x4*)(Wf + (size_t)c * 128);
#pragma unroll
    for (int k = 0; k < 32; ++k) {
        f32x4 wv = wr[k];
        acc += m[4 * k] * wv.x + m[4 * k + 1] * wv.y + m[4 * k + 2] * wv.z + m[4 * k + 3] * wv.w;
    }
    out[g * 128 + c] = acc;
}

extern "C" void kernel_launch(void* const* d_in, const int* in_sizes, int n_in,
                              void* d_out, int out_size, void* d_ws, size_t ws_size,
                              hipStream_t stream)
{
    const float* x     = (const float*)d_in[0];
    const int*   batch = (const int*)d_in[1];
    const float* Wlin  = (const float*)d_in[2];
    const float* blin  = (const float*)d_in[3];
    const float* Wgate = (const float*)d_in[4];
    const float* bgate = (const float*)d_in[5];
    const float* Wfin  = (const float*)d_in[6];
    const float* bfin  = (const float*)d_in[7];
    float* out  = (float*)d_out;
    float* sums = (float*)d_ws;                               // 512 KB
    int*   off  = (int*)((char*)d_ws + 512 * 1024);           // 1025 ints

    const int nNodes  = in_sizes[1];
    const int nGraphs = out_size / 128;

    // ~977 blocks, contiguous ranges, P multiple of 32
    const int P  = ((((nNodes + 1023) / 1024) + 31) & ~31);
    const int nB = (nNodes + P - 1) / P;

    prep<<<1024, 256, 0, stream>>>(batch, nNodes, sums, off);
    gnn_main<<<nB, 512, 0, stream>>>(x, batch, Wlin, blin, Wgate, bgate, sums, nNodes, P);
    final_mm<<<nGraphs, 128, 0, stream>>>(sums, off, Wfin, bfin, out);
}